// Round 8
// baseline (308.960 us; speedup 1.0000x reference)
//
#include <hip/hip_runtime.h>
#include <hip/hip_bf16.h>
#include <float.h>

#define B_ 1024
#define H_ 512
#define N_ (B_ * 64)
#define FFN_ 2048
#define OUT_ 86

typedef __bf16 bf16_t;
typedef __attribute__((ext_vector_type(8))) __bf16 bf16x8;
typedef __attribute__((ext_vector_type(4))) float f32x4;

__device__ __forceinline__ float wred_sum(float v) {
#pragma unroll
  for (int m = 32; m; m >>= 1) v += __shfl_xor(v, m);
  return v;
}

__device__ __forceinline__ void gload_lds16(const void* g, void* l) {
  __builtin_amdgcn_global_load_lds((const __attribute__((address_space(1))) unsigned int*)g,
                                   (__attribute__((address_space(3))) unsigned int*)l, 16, 0, 0);
}

// ev[j] = sum_h prj_w[j][h]*w_i_b[h]; c0 = w_i_b . prj_b
__global__ void k_prep(const float* __restrict__ w_i_b,
                       const float* __restrict__ prj_w, const float* __restrict__ prj_b,
                       float* __restrict__ ev, float* __restrict__ c0) {
  int b = blockIdx.x, l = threadIdx.x;
  float s = 0.f;
  if (b < 512) {
    for (int h = l; h < H_; h += 64) s += prj_w[b * H_ + h] * w_i_b[h];
    s = wred_sum(s);
    if (l == 0) ev[b] = s;
  } else {
    for (int h = l; h < H_; h += 64) s += w_i_b[h] * prj_b[h];
    s = wred_sum(s);
    if (l == 0) c0[0] = s;
  }
}

__global__ void k_cvec(const float* __restrict__ ro, const float* __restrict__ lo,
                       const float* __restrict__ ev, const float* __restrict__ c0,
                       float* __restrict__ cL, float* __restrict__ cR) {
  int b = blockIdx.x, side = blockIdx.y, l = threadIdx.x;
  const float* x = side ? lo : ro;
  float s = 0.f;
  for (int j = l; j < H_; j += 64) s += x[b * H_ + j] * ev[j];
  s = wred_sum(s);
  if (l == 0) (side ? cR : cL)[b] = s + c0[0];
}

// f32 tiled GEMM, 64x64 tile, BK=16, 4x4 accum. A split across two row blocks.
template <bool BT, bool BIAS>
__global__ __launch_bounds__(256) void gemm64(const float* __restrict__ A1, const float* __restrict__ A2,
                                              int M1, const float* __restrict__ Bm,
                                              const float* __restrict__ bias, float* __restrict__ C,
                                              int N, int K) {
  __shared__ float As[16][68];
  __shared__ float Bs[16][68];
  const int bm = blockIdx.x * 64, bn = blockIdx.y * 64;
  const float* __restrict__ A = (bm < M1) ? (A1 + (size_t)bm * K) : (A2 + (size_t)(bm - M1) * K);
  const int t = threadIdx.x;
  const int tx = t & 15, ty = t >> 4;
  float acc[4][4] = {};
  for (int k0 = 0; k0 < K; k0 += 16) {
#pragma unroll
    for (int i = 0; i < 4; i++) {
      int m = (t >> 4) + i * 16;
      As[t & 15][m] = A[(size_t)m * K + k0 + (t & 15)];
    }
    if (BT) {
#pragma unroll
      for (int i = 0; i < 4; i++) {
        int n = (t >> 4) + i * 16;
        Bs[t & 15][n] = Bm[(size_t)(bn + n) * K + k0 + (t & 15)];
      }
    } else {
#pragma unroll
      for (int i = 0; i < 4; i++) {
        int kk = (t >> 6) + i * 4;
        Bs[kk][t & 63] = Bm[(size_t)(k0 + kk) * N + bn + (t & 63)];
      }
    }
    __syncthreads();
#pragma unroll
    for (int kk = 0; kk < 16; kk++) {
      float4 av = *(const float4*)&As[kk][ty * 4];
      float4 bv = *(const float4*)&Bs[kk][tx * 4];
      float a_[4] = {av.x, av.y, av.z, av.w};
      float b_[4] = {bv.x, bv.y, bv.z, bv.w};
#pragma unroll
      for (int i = 0; i < 4; i++)
#pragma unroll
        for (int j = 0; j < 4; j++) acc[i][j] += a_[i] * b_[j];
    }
    __syncthreads();
  }
#pragma unroll
  for (int i = 0; i < 4; i++) {
    int m = bm + ty * 4 + i;
    float tmp[4];
#pragma unroll
    for (int j = 0; j < 4; j++) {
      float x = acc[i][j];
      if (BIAS) x += bias[bn + tx * 4 + j];
      tmp[j] = x;
    }
    float4 v;
    v.x = tmp[0]; v.y = tmp[1]; v.z = tmp[2]; v.w = tmp[3];
    *(float4*)&C[(size_t)m * N + bn + tx * 4] = v;
  }
}

// Fused scores+softmax+pool. 2 waves per (b,side), 32 atoms each as 8 chunks
// of 4 atoms with an explicit 2-slot register pipeline (abuf[2][4][8], all
// indices compile-time). Peak liveness ~100 regs -> no spill (r7 lesson:
// 8-atom tile + merge state spilled at 128). Flash merge via LDS.
__global__ void k_atoms5(const float* __restrict__ atomL, const float* __restrict__ atomR,
                         const float* __restrict__ uLR,
                         const float* __restrict__ cL, const float* __restrict__ cR,
                         float* __restrict__ scoresL, float* __restrict__ scoresR,
                         float* __restrict__ pL, float* __restrict__ pR) {
  const int t = threadIdx.x, wave = t >> 6, lane = t & 63;
  const int pairLocal = wave >> 1;               // 0..1
  const int half = wave & 1;                     // which 32-atom half
  const int pair = blockIdx.x * 2 + pairLocal;   // 0..2047
  const int side = pair >> 10, b = pair & 1023;

  const float* __restrict__ atom = side ? atomR : atomL;
  const float cb = (side ? cR : cL)[b];

  __shared__ float mzs[4][2];
  __shared__ float pp[4][512];

  const float* __restrict__ u = uLR + (size_t)pair * H_;
  float ur[8];
  *(f32x4*)&ur[0] = *(const f32x4*)&u[lane * 8];
  *(f32x4*)&ur[4] = *(const f32x4*)&u[lane * 8 + 4];

  const float* __restrict__ base = atom + ((size_t)b * 64 + half * 32) * H_ + lane * 8;

  float q[8] = {};
  float m_run = -FLT_MAX, z_run = 0.f, myraw = 0.f;

  float abuf[2][4][8];
  // prologue: chunk 0 -> slot 0
#pragma unroll
  for (int i = 0; i < 4; i++) {
    const float* rp = base + (size_t)i * H_;
    *(f32x4*)&abuf[0][i][0] = *(const f32x4*)rp;
    *(f32x4*)&abuf[0][i][4] = *(const f32x4*)(rp + 4);
  }

#pragma unroll
  for (int c = 0; c < 8; c++) {
    const int cur = c & 1, nxt = cur ^ 1;
    if (c < 7) {  // prefetch next chunk into the other slot
#pragma unroll
      for (int i = 0; i < 4; i++) {
        const float* rp = base + (size_t)((c + 1) * 4 + i) * H_;
        *(f32x4*)&abuf[nxt][i][0] = *(const f32x4*)rp;
        *(f32x4*)&abuf[nxt][i][4] = *(const f32x4*)(rp + 4);
      }
    }
    float d[4];
#pragma unroll
    for (int i = 0; i < 4; i++) {
      float s = 0.f;
#pragma unroll
      for (int j = 0; j < 8; j++) s += abuf[cur][i][j] * ur[j];
      d[i] = s;
    }
#pragma unroll
    for (int i = 0; i < 4; i++) d[i] = wred_sum(d[i]) + cb;
#pragma unroll
    for (int i = 0; i < 4; i++) myraw = (lane == c * 4 + i) ? d[i] : myraw;
    float mc = fmaxf(fmaxf(d[0], d[1]), fmaxf(d[2], d[3]));
    float m_new = fmaxf(m_run, mc);
    float r = __expf(m_run - m_new);
    float e[4];
    float zc = 0.f;
#pragma unroll
    for (int i = 0; i < 4; i++) { e[i] = __expf(d[i] - m_new); zc += e[i]; }
    z_run = z_run * r + zc;
    m_run = m_new;
#pragma unroll
    for (int j = 0; j < 8; j++) q[j] *= r;
#pragma unroll
    for (int i = 0; i < 4; i++)
#pragma unroll
      for (int j = 0; j < 8; j++) q[j] += e[i] * abuf[cur][i][j];
  }

  if (lane == 0) { mzs[wave][0] = m_run; mzs[wave][1] = z_run; }
  *(f32x4*)&pp[wave][lane * 8] = *(const f32x4*)&q[0];
  *(f32x4*)&pp[wave][lane * 8 + 4] = *(const f32x4*)&q[4];
  __syncthreads();

  // scores epilogue: lanes 0..31 of each wave own this half's 32 raw scores
  {
    const float m0 = mzs[pairLocal * 2][0], z0 = mzs[pairLocal * 2][1];
    const float m1 = mzs[pairLocal * 2 + 1][0], z1 = mzs[pairLocal * 2 + 1][1];
    const float M = fmaxf(m0, m1);
    const float zinv = 1.f / (z0 * __expf(m0 - M) + z1 * __expf(m1 - M));
    if (lane < 32)
      (side ? scoresR : scoresL)[(size_t)b * 64 + half * 32 + lane] = __expf(myraw - M) * zinv;
  }

  // pool merge: threads [0,128) -> block-local pair 0, [128,256) -> pair 1
  const int mp = t >> 7;
  const int pb = blockIdx.x * 2 + mp;
  const int sside = pb >> 10, bb = pb & 1023;
  const float m0 = mzs[mp * 2][0], z0 = mzs[mp * 2][1];
  const float m1 = mzs[mp * 2 + 1][0], z1 = mzs[mp * 2 + 1][1];
  const float M = fmaxf(m0, m1);
  const float f0 = __expf(m0 - M), f1 = __expf(m1 - M);
  const float zinv = 1.f / (z0 * f0 + z1 * f1);
  const int col0 = (t & 127) * 4;
  f32x4 qa = *(const f32x4*)&pp[mp * 2][col0];
  f32x4 qb = *(const f32x4*)&pp[mp * 2 + 1][col0];
  f32x4 o;
  o.x = (qa.x * f0 + qb.x * f1) * zinv;
  o.y = (qa.y * f0 + qb.y * f1) * zinv;
  o.z = (qa.z * f0 + qb.z * f1) * zinv;
  o.w = (qa.w * f0 + qb.w * f1) * zinv;
  float* pdst = (sside ? pR : pL) + (size_t)bb * H_;
  *(f32x4*)&pdst[col0] = o;
}

// perturbation + bf16 pair assembly
__global__ __launch_bounds__(512) void k_pert(const float* __restrict__ lo, const float* __restrict__ ro,
                                              const float* __restrict__ noise,
                                              const float* __restrict__ pL, const float* __restrict__ pR,
                                              float* __restrict__ h_out, float* __restrict__ h_pert,
                                              bf16_t* __restrict__ pairbf) {
  const int b = blockIdx.x, t = threadIdx.x;
  float nv = noise[(size_t)b * H_ + t];
  float sq = nv * nv;
  sq = wred_sum(sq);
  __shared__ float red[8];
  if ((t & 63) == 0) red[t >> 6] = sq;
  __syncthreads();
  float tot = 0.f;
#pragma unroll
  for (int i = 0; i < 8; i++) tot += red[i];
  float nrm = fmaxf(sqrtf(tot), 1e-12f);
  float nn = nv / nrm * 0.1f;
  float h = ro[(size_t)b * H_ + t] * pL[(size_t)b * H_ + t];
  float tt = lo[(size_t)b * H_ + t] * pR[(size_t)b * H_ + t];
  float sh = (h > 0.f) ? 1.f : ((h < 0.f) ? -1.f : 0.f);
  float st = (tt > 0.f) ? 1.f : ((tt < 0.f) ? -1.f : 0.f);
  float hp = h + sh * nn;
  float tp = tt + st * nn;
  h_out[(size_t)b * H_ + t] = h;
  h_pert[(size_t)b * H_ + t] = hp;
  pairbf[(size_t)b * 1024 + t] = (bf16_t)hp;
  pairbf[(size_t)b * 1024 + 512 + t] = (bf16_t)tp;
}

// W1 [1024][2048] f32 -> W1t [2048][1024] bf16 (transpose + cast, LDS tiled)
__global__ __launch_bounds__(256) void k_w1t(const float* __restrict__ W1, bf16_t* __restrict__ W1t) {
  __shared__ float tile[32][33];
  const int bx = blockIdx.x;
  const int by = blockIdx.y;
  const int tx = threadIdx.x & 31, ty = threadIdx.x >> 5;
#pragma unroll
  for (int i = ty; i < 32; i += 8)
    tile[i][tx] = W1[(size_t)(by * 32 + i) * FFN_ + bx * 32 + tx];
  __syncthreads();
#pragma unroll
  for (int i = ty; i < 32; i += 8)
    W1t[(size_t)(bx * 32 + i) * 1024 + by * 32 + tx] = (bf16_t)tile[tx][i];
}

// FFN1 via MFMA bf16 (64x64 tile, XOR-swizzled source + matching swizzled read)
__global__ __launch_bounds__(256) void k_ffn1(const bf16_t* __restrict__ Abf, const bf16_t* __restrict__ Bt,
                                              const float* __restrict__ bias, float* __restrict__ C) {
  __shared__ bf16_t As[64 * 64];
  __shared__ bf16_t Bs[64 * 64];
  const int bm = blockIdx.x * 64, bn = blockIdx.y * 64;
  const int t = threadIdx.x;
  const int lane = t & 63, wave = t >> 6;
  const int wm = wave & 1, wn = wave >> 1;
  const int l15 = lane & 15, l4 = lane >> 4;
  f32x4 acc[2][2] = {{{0.f, 0.f, 0.f, 0.f}, {0.f, 0.f, 0.f, 0.f}},
                     {{0.f, 0.f, 0.f, 0.f}, {0.f, 0.f, 0.f, 0.f}}};

  for (int k0 = 0; k0 < 1024; k0 += 64) {
#pragma unroll
    for (int r = 0; r < 2; r++) {
      const int off = (r * 256 + t) * 16;
      const int row = off >> 7;
      const int g = (off >> 4) & 7;
      const int scb = ((g ^ (row & 7)) << 4);
      gload_lds16((const char*)Abf + (size_t)(bm + row) * 2048 + k0 * 2 + scb, (char*)As + off);
      gload_lds16((const char*)Bt + (size_t)(bn + row) * 2048 + k0 * 2 + scb, (char*)Bs + off);
    }
    __syncthreads();
#pragma unroll
    for (int ks = 0; ks < 2; ks++) {
      const int ar0 = wm * 32 + l15, ar1 = ar0 + 16;
      const int br0 = wn * 32 + l15, br1 = br0 + 16;
      const int gA = ks * 4 + l4;
      bf16x8 a0 = *(const bf16x8*)((const char*)As + ar0 * 128 + ((gA ^ (ar0 & 7)) << 4));
      bf16x8 a1 = *(const bf16x8*)((const char*)As + ar1 * 128 + ((gA ^ (ar1 & 7)) << 4));
      bf16x8 b0 = *(const bf16x8*)((const char*)Bs + br0 * 128 + ((gA ^ (br0 & 7)) << 4));
      bf16x8 b1 = *(const bf16x8*)((const char*)Bs + br1 * 128 + ((gA ^ (br1 & 7)) << 4));
      acc[0][0] = __builtin_amdgcn_mfma_f32_16x16x32_bf16(a0, b0, acc[0][0], 0, 0, 0);
      acc[0][1] = __builtin_amdgcn_mfma_f32_16x16x32_bf16(a0, b1, acc[0][1], 0, 0, 0);
      acc[1][0] = __builtin_amdgcn_mfma_f32_16x16x32_bf16(a1, b0, acc[1][0], 0, 0, 0);
      acc[1][1] = __builtin_amdgcn_mfma_f32_16x16x32_bf16(a1, b1, acc[1][1], 0, 0, 0);
    }
    __syncthreads();
  }
#pragma unroll
  for (int mi = 0; mi < 2; mi++)
#pragma unroll
    for (int nj = 0; nj < 2; nj++)
#pragma unroll
      for (int r = 0; r < 4; r++) {
        const int m = bm + wm * 32 + mi * 16 + l4 * 4 + r;
        const int n = bn + wn * 32 + nj * 16 + l15;
        float v = acc[mi][nj][r] + bias[n];
        C[(size_t)m * FFN_ + n] = fmaxf(v, 0.f);
      }
}

__global__ void k_w2t(const float* __restrict__ W2, float* __restrict__ W2t) {
  int idx = blockIdx.x * 256 + threadIdx.x;
  if (idx < OUT_ * FFN_) {
    int n = idx / FFN_, k = idx % FFN_;
    W2t[idx] = W2[(size_t)k * OUT_ + n];
  }
}

__global__ __launch_bounds__(256) void k_ffn2(const float* __restrict__ hid, const float* __restrict__ W2t,
                                              const float* __restrict__ b2, float* __restrict__ out) {
  const int b0 = blockIdx.x * 2;
  const int t = threadIdx.x, wave = t >> 6, lane = t & 63;
  float4 h0[8], h1[8];
  const float* r0 = hid + (size_t)b0 * FFN_;
#pragma unroll
  for (int j = 0; j < 8; j++) {
    h0[j] = *(const float4*)&r0[lane * 4 + j * 256];
    h1[j] = *(const float4*)&r0[FFN_ + lane * 4 + j * 256];
  }
  for (int n = wave; n < OUT_; n += 4) {
    const float* wrow = W2t + (size_t)n * FFN_;
    float s0 = 0.f, s1 = 0.f;
#pragma unroll
    for (int j = 0; j < 8; j++) {
      float4 w4 = *(const float4*)&wrow[lane * 4 + j * 256];
      s0 += w4.x * h0[j].x + w4.y * h0[j].y + w4.z * h0[j].z + w4.w * h0[j].w;
      s1 += w4.x * h1[j].x + w4.y * h1[j].y + w4.z * h1[j].z + w4.w * h1[j].w;
    }
    s0 = wred_sum(s0);
    s1 = wred_sum(s1);
    if (lane == 0) {
      out[(size_t)b0 * OUT_ + n] = s0 + b2[n];
      out[(size_t)(b0 + 1) * OUT_ + n] = s1 + b2[n];
    }
  }
}

extern "C" void kernel_launch(void* const* d_in, const int* in_sizes, int n_in,
                              void* d_out, int out_size, void* d_ws, size_t ws_size,
                              hipStream_t stream) {
  const float* lo = (const float*)d_in[0];
  const float* ro = (const float*)d_in[1];
  const float* la = (const float*)d_in[2];
  const float* ra = (const float*)d_in[3];
  const float* noise = (const float*)d_in[6];
  const float* w_i_w = (const float*)d_in[7];
  const float* w_i_b = (const float*)d_in[8];
  const float* prj_w = (const float*)d_in[9];
  const float* prj_b = (const float*)d_in[10];
  const float* W1 = (const float*)d_in[11];
  const float* b1 = (const float*)d_in[12];
  const float* W2 = (const float*)d_in[13];
  const float* b2 = (const float*)d_in[14];

  float* out = (float*)d_out;
  float* o_logits = out;                  // [1024,86]
  float* o_hout  = out + 88064;           // [1024,512]
  float* o_hpert = o_hout + 524288;       // [1024,512]
  float* o_ls    = o_hpert + 524288;      // [65536]
  float* o_rs    = o_ls + 65536;          // [65536]
  float* o_lo    = o_rs + 65536;          // [1024,512]
  float* o_ro    = o_lo + 524288;         // [1024,512]

  float* ws = (float*)d_ws;
  float* T    = ws; ws += 2048 * 512;     // [ro;lo] @ prj_w + prj_b
  float* uLR  = ws; ws += 2048 * 512;     // T @ w_i_w^T
  float* pL   = ws; ws += B_ * H_;
  float* pR   = ws; ws += B_ * H_;
  float* hid  = ws; ws += B_ * FFN_;
  float* W2t  = ws; ws += OUT_ * FFN_;
  bf16_t* pairbf = (bf16_t*)ws; ws += B_ * 1024 / 2;
  bf16_t* W1t    = (bf16_t*)ws; ws += FFN_ * 1024 / 2;
  float* ev   = ws; ws += 512;
  float* cL   = ws; ws += 1024;
  float* cR   = ws; ws += 1024;
  float* c0   = ws; ws += 4;

  k_prep<<<513, 64, 0, stream>>>(w_i_b, prj_w, prj_b, ev, c0);
  // T = [ro;lo] @ prj_w + prj_b   (NN, 2048x512x512)
  gemm64<false, true><<<dim3(32, 8), 256, 0, stream>>>(ro, lo, 1024, prj_w, prj_b, T, 512, 512);
  // uLR = T @ w_i_w^T             (NT, 2048x512x512)
  gemm64<true, false><<<dim3(32, 8), 256, 0, stream>>>(T, T, 1 << 30, w_i_w, nullptr, uLR, 512, 512);
  k_cvec<<<dim3(1024, 2), 64, 0, stream>>>(ro, lo, ev, c0, cL, cR);
  k_w1t<<<dim3(64, 32), 256, 0, stream>>>(W1, W1t);
  k_atoms5<<<1024, 256, 0, stream>>>(la, ra, uLR, cL, cR, o_ls, o_rs, pL, pR);
  k_pert<<<1024, 512, 0, stream>>>(lo, ro, noise, pL, pR, o_hout, o_hpert, pairbf);
  k_ffn1<<<dim3(16, 32), 256, 0, stream>>>(pairbf, W1t, b1, hid);
  k_w2t<<<688, 256, 0, stream>>>(W2, W2t);
  k_ffn2<<<512, 256, 0, stream>>>(hid, W2t, b2, o_logits);
  hipMemcpyAsync(o_lo, lo, (size_t)B_ * H_ * 4, hipMemcpyDeviceToDevice, stream);
  hipMemcpyAsync(o_ro, ro, (size_t)B_ * H_ * 4, hipMemcpyDeviceToDevice, stream);
}

// Round 9
// 218.841 us; speedup vs baseline: 1.4118x; 1.4118x over previous
//
#include <hip/hip_runtime.h>
#include <hip/hip_bf16.h>
#include <float.h>

#define B_ 1024
#define H_ 512
#define N_ (B_ * 64)
#define FFN_ 2048
#define OUT_ 86

typedef __bf16 bf16_t;
typedef __attribute__((ext_vector_type(8))) __bf16 bf16x8;
typedef __attribute__((ext_vector_type(4))) float f32x4;

__device__ __forceinline__ float wred_sum(float v) {
#pragma unroll
  for (int m = 32; m; m >>= 1) v += __shfl_xor(v, m);
  return v;
}
__device__ __forceinline__ float wred_max(float v) {
#pragma unroll
  for (int m = 32; m; m >>= 1) v = fmaxf(v, __shfl_xor(v, m));
  return v;
}

__device__ __forceinline__ void gload_lds16(const void* g, void* l) {
  __builtin_amdgcn_global_load_lds((const __attribute__((address_space(1))) unsigned int*)g,
                                   (__attribute__((address_space(3))) unsigned int*)l, 16, 0, 0);
}

// ev[j] = sum_h prj_w[j][h]*w_i_b[h]; c0 = w_i_b . prj_b
__global__ void k_prep(const float* __restrict__ w_i_b,
                       const float* __restrict__ prj_w, const float* __restrict__ prj_b,
                       float* __restrict__ ev, float* __restrict__ c0) {
  int b = blockIdx.x, l = threadIdx.x;
  float s = 0.f;
  if (b < 512) {
    for (int h = l; h < H_; h += 64) s += prj_w[b * H_ + h] * w_i_b[h];
    s = wred_sum(s);
    if (l == 0) ev[b] = s;
  } else {
    for (int h = l; h < H_; h += 64) s += w_i_b[h] * prj_b[h];
    s = wred_sum(s);
    if (l == 0) c0[0] = s;
  }
}

__global__ void k_cvec(const float* __restrict__ ro, const float* __restrict__ lo,
                       const float* __restrict__ ev, const float* __restrict__ c0,
                       float* __restrict__ cL, float* __restrict__ cR) {
  int b = blockIdx.x, side = blockIdx.y, l = threadIdx.x;
  const float* x = side ? lo : ro;
  float s = 0.f;
  for (int j = l; j < H_; j += 64) s += x[b * H_ + j] * ev[j];
  s = wred_sum(s);
  if (l == 0) (side ? cR : cL)[b] = s + c0[0];
}

// f32 tiled GEMM, 64x64 tile, BK=16, 4x4 accum. A split across two row blocks.
template <bool BT, bool BIAS>
__global__ __launch_bounds__(256) void gemm64(const float* __restrict__ A1, const float* __restrict__ A2,
                                              int M1, const float* __restrict__ Bm,
                                              const float* __restrict__ bias, float* __restrict__ C,
                                              int N, int K) {
  __shared__ float As[16][68];
  __shared__ float Bs[16][68];
  const int bm = blockIdx.x * 64, bn = blockIdx.y * 64;
  const float* __restrict__ A = (bm < M1) ? (A1 + (size_t)bm * K) : (A2 + (size_t)(bm - M1) * K);
  const int t = threadIdx.x;
  const int tx = t & 15, ty = t >> 4;
  float acc[4][4] = {};
  for (int k0 = 0; k0 < K; k0 += 16) {
#pragma unroll
    for (int i = 0; i < 4; i++) {
      int m = (t >> 4) + i * 16;
      As[t & 15][m] = A[(size_t)m * K + k0 + (t & 15)];
    }
    if (BT) {
#pragma unroll
      for (int i = 0; i < 4; i++) {
        int n = (t >> 4) + i * 16;
        Bs[t & 15][n] = Bm[(size_t)(bn + n) * K + k0 + (t & 15)];
      }
    } else {
#pragma unroll
      for (int i = 0; i < 4; i++) {
        int kk = (t >> 6) + i * 4;
        Bs[kk][t & 63] = Bm[(size_t)(k0 + kk) * N + bn + (t & 63)];
      }
    }
    __syncthreads();
#pragma unroll
    for (int kk = 0; kk < 16; kk++) {
      float4 av = *(const float4*)&As[kk][ty * 4];
      float4 bv = *(const float4*)&Bs[kk][tx * 4];
      float a_[4] = {av.x, av.y, av.z, av.w};
      float b_[4] = {bv.x, bv.y, bv.z, bv.w};
#pragma unroll
      for (int i = 0; i < 4; i++)
#pragma unroll
        for (int j = 0; j < 4; j++) acc[i][j] += a_[i] * b_[j];
    }
    __syncthreads();
  }
#pragma unroll
  for (int i = 0; i < 4; i++) {
    int m = bm + ty * 4 + i;
    float tmp[4];
#pragma unroll
    for (int j = 0; j < 4; j++) {
      float x = acc[i][j];
      if (BIAS) x += bias[bn + tx * 4 + j];
      tmp[j] = x;
    }
    float4 v;
    v.x = tmp[0]; v.y = tmp[1]; v.z = tmp[2]; v.w = tmp[3];
    *(float4*)&C[(size_t)m * N + bn + tx * 4] = v;
  }
}

// PASS 1: raw scores. Block per (b,side); wave w handles atoms [w*16, w*16+16)
// in chunks of 4 (#pragma unroll 1 bounds liveness at ~54 regs < 64 default cap
// -> no spill at full 8-waves/SIMD occupancy). Pure streaming, no cross-wave state.
__global__ __launch_bounds__(256) void k_sraw(const float* __restrict__ atomL, const float* __restrict__ atomR,
                                              const float* __restrict__ uLR,
                                              const float* __restrict__ cL, const float* __restrict__ cR,
                                              float* __restrict__ sraw) {
  const int pair = blockIdx.x;                 // 0..2047
  const int side = pair >> 10, b = pair & 1023;
  const int t = threadIdx.x, wave = t >> 6, lane = t & 63;
  const float* __restrict__ atom = side ? atomR : atomL;
  const float cb = (side ? cR : cL)[b];
  float ur[8];
  const float* u = uLR + (size_t)pair * H_ + lane * 8;
  *(f32x4*)&ur[0] = *(const f32x4*)u;
  *(f32x4*)&ur[4] = *(const f32x4*)(u + 4);
  const float* __restrict__ base = atom + ((size_t)b * 64 + wave * 16) * H_ + lane * 8;
  float* __restrict__ sout = sraw + (size_t)pair * 64 + wave * 16;
#pragma unroll 1
  for (int c = 0; c < 4; c++) {
    float a[4][8];
#pragma unroll
    for (int i = 0; i < 4; i++) {
      const float* rp = base + (size_t)(c * 4 + i) * H_;
      *(f32x4*)&a[i][0] = *(const f32x4*)rp;
      *(f32x4*)&a[i][4] = *(const f32x4*)(rp + 4);
    }
    float d[4];
#pragma unroll
    for (int i = 0; i < 4; i++) {
      float s = 0.f;
#pragma unroll
      for (int j = 0; j < 8; j++) s += a[i][j] * ur[j];
      d[i] = s;
    }
#pragma unroll
    for (int i = 0; i < 4; i++) d[i] = wred_sum(d[i]);
    if (lane == 0) {
#pragma unroll
      for (int i = 0; i < 4; i++) sout[c * 4 + i] = d[i] + cb;
    }
  }
}

// PASS 1.5: 64-wide softmax per pair -> normalized scores into output buffers.
__global__ void k_smax(const float* __restrict__ sraw,
                       float* __restrict__ scoresL, float* __restrict__ scoresR) {
  const int pair = blockIdx.x;
  const int side = pair >> 10, b = pair & 1023;
  const int lane = threadIdx.x;
  float s = sraw[(size_t)pair * 64 + lane];
  float mx = wred_max(s);
  float e = __expf(s - mx);
  float z = wred_sum(e);
  (side ? scoresR : scoresL)[(size_t)b * 64 + lane] = e / z;
}

// PASS 2: pool = scores^T @ atom_tile. Block per (b,side), thread owns cols t
// and t+256; 64 row-iterations, fully coalesced (block reads whole 2KB row),
// scores broadcast from LDS. ~30 regs, spill-free, L3-warm re-read of atoms.
__global__ __launch_bounds__(256) void k_pool(const float* __restrict__ atomL, const float* __restrict__ atomR,
                                              const float* __restrict__ scoresL, const float* __restrict__ scoresR,
                                              float* __restrict__ pL, float* __restrict__ pR) {
  const int pair = blockIdx.x;
  const int side = pair >> 10, b = pair & 1023;
  const int t = threadIdx.x;
  const float* __restrict__ atom = (side ? atomR : atomL) + (size_t)b * 64 * H_;
  const float* __restrict__ sc = (side ? scoresR : scoresL) + (size_t)b * 64;
  __shared__ float wls[64];
  if (t < 64) wls[t] = sc[t];
  __syncthreads();
  float acc0 = 0.f, acc1 = 0.f;
#pragma unroll 1
  for (int i = 0; i < 64; i += 4) {
#pragma unroll
    for (int k = 0; k < 4; k++) {
      const float w = wls[i + k];
      acc0 += w * atom[(size_t)(i + k) * H_ + t];
      acc1 += w * atom[(size_t)(i + k) * H_ + t + 256];
    }
  }
  float* p = (side ? pR : pL) + (size_t)b * H_;
  p[t] = acc0;
  p[t + 256] = acc1;
}

// perturbation + bf16 pair assembly
__global__ __launch_bounds__(512) void k_pert(const float* __restrict__ lo, const float* __restrict__ ro,
                                              const float* __restrict__ noise,
                                              const float* __restrict__ pL, const float* __restrict__ pR,
                                              float* __restrict__ h_out, float* __restrict__ h_pert,
                                              bf16_t* __restrict__ pairbf) {
  const int b = blockIdx.x, t = threadIdx.x;
  float nv = noise[(size_t)b * H_ + t];
  float sq = nv * nv;
  sq = wred_sum(sq);
  __shared__ float red[8];
  if ((t & 63) == 0) red[t >> 6] = sq;
  __syncthreads();
  float tot = 0.f;
#pragma unroll
  for (int i = 0; i < 8; i++) tot += red[i];
  float nrm = fmaxf(sqrtf(tot), 1e-12f);
  float nn = nv / nrm * 0.1f;
  float h = ro[(size_t)b * H_ + t] * pL[(size_t)b * H_ + t];
  float tt = lo[(size_t)b * H_ + t] * pR[(size_t)b * H_ + t];
  float sh = (h > 0.f) ? 1.f : ((h < 0.f) ? -1.f : 0.f);
  float st = (tt > 0.f) ? 1.f : ((tt < 0.f) ? -1.f : 0.f);
  float hp = h + sh * nn;
  float tp = tt + st * nn;
  h_out[(size_t)b * H_ + t] = h;
  h_pert[(size_t)b * H_ + t] = hp;
  pairbf[(size_t)b * 1024 + t] = (bf16_t)hp;
  pairbf[(size_t)b * 1024 + 512 + t] = (bf16_t)tp;
}

// W1 [1024][2048] f32 -> W1t [2048][1024] bf16 (transpose + cast, LDS tiled)
__global__ __launch_bounds__(256) void k_w1t(const float* __restrict__ W1, bf16_t* __restrict__ W1t) {
  __shared__ float tile[32][33];
  const int bx = blockIdx.x;
  const int by = blockIdx.y;
  const int tx = threadIdx.x & 31, ty = threadIdx.x >> 5;
#pragma unroll
  for (int i = ty; i < 32; i += 8)
    tile[i][tx] = W1[(size_t)(by * 32 + i) * FFN_ + bx * 32 + tx];
  __syncthreads();
#pragma unroll
  for (int i = ty; i < 32; i += 8)
    W1t[(size_t)(bx * 32 + i) * 1024 + by * 32 + tx] = (bf16_t)tile[tx][i];
}

// FFN1 via MFMA bf16 (64x64 tile, XOR-swizzled source + matching swizzled read)
__global__ __launch_bounds__(256) void k_ffn1(const bf16_t* __restrict__ Abf, const bf16_t* __restrict__ Bt,
                                              const float* __restrict__ bias, float* __restrict__ C) {
  __shared__ bf16_t As[64 * 64];
  __shared__ bf16_t Bs[64 * 64];
  const int bm = blockIdx.x * 64, bn = blockIdx.y * 64;
  const int t = threadIdx.x;
  const int lane = t & 63, wave = t >> 6;
  const int wm = wave & 1, wn = wave >> 1;
  const int l15 = lane & 15, l4 = lane >> 4;
  f32x4 acc[2][2] = {{{0.f, 0.f, 0.f, 0.f}, {0.f, 0.f, 0.f, 0.f}},
                     {{0.f, 0.f, 0.f, 0.f}, {0.f, 0.f, 0.f, 0.f}}};

  for (int k0 = 0; k0 < 1024; k0 += 64) {
#pragma unroll
    for (int r = 0; r < 2; r++) {
      const int off = (r * 256 + t) * 16;
      const int row = off >> 7;
      const int g = (off >> 4) & 7;
      const int scb = ((g ^ (row & 7)) << 4);
      gload_lds16((const char*)Abf + (size_t)(bm + row) * 2048 + k0 * 2 + scb, (char*)As + off);
      gload_lds16((const char*)Bt + (size_t)(bn + row) * 2048 + k0 * 2 + scb, (char*)Bs + off);
    }
    __syncthreads();
#pragma unroll
    for (int ks = 0; ks < 2; ks++) {
      const int ar0 = wm * 32 + l15, ar1 = ar0 + 16;
      const int br0 = wn * 32 + l15, br1 = br0 + 16;
      const int gA = ks * 4 + l4;
      bf16x8 a0 = *(const bf16x8*)((const char*)As + ar0 * 128 + ((gA ^ (ar0 & 7)) << 4));
      bf16x8 a1 = *(const bf16x8*)((const char*)As + ar1 * 128 + ((gA ^ (ar1 & 7)) << 4));
      bf16x8 b0 = *(const bf16x8*)((const char*)Bs + br0 * 128 + ((gA ^ (br0 & 7)) << 4));
      bf16x8 b1 = *(const bf16x8*)((const char*)Bs + br1 * 128 + ((gA ^ (br1 & 7)) << 4));
      acc[0][0] = __builtin_amdgcn_mfma_f32_16x16x32_bf16(a0, b0, acc[0][0], 0, 0, 0);
      acc[0][1] = __builtin_amdgcn_mfma_f32_16x16x32_bf16(a0, b1, acc[0][1], 0, 0, 0);
      acc[1][0] = __builtin_amdgcn_mfma_f32_16x16x32_bf16(a1, b0, acc[1][0], 0, 0, 0);
      acc[1][1] = __builtin_amdgcn_mfma_f32_16x16x32_bf16(a1, b1, acc[1][1], 0, 0, 0);
    }
    __syncthreads();
  }
#pragma unroll
  for (int mi = 0; mi < 2; mi++)
#pragma unroll
    for (int nj = 0; nj < 2; nj++)
#pragma unroll
      for (int r = 0; r < 4; r++) {
        const int m = bm + wm * 32 + mi * 16 + l4 * 4 + r;
        const int n = bn + wn * 32 + nj * 16 + l15;
        float v = acc[mi][nj][r] + bias[n];
        C[(size_t)m * FFN_ + n] = fmaxf(v, 0.f);
      }
}

__global__ void k_w2t(const float* __restrict__ W2, float* __restrict__ W2t) {
  int idx = blockIdx.x * 256 + threadIdx.x;
  if (idx < OUT_ * FFN_) {
    int n = idx / FFN_, k = idx % FFN_;
    W2t[idx] = W2[(size_t)k * OUT_ + n];
  }
}

__global__ __launch_bounds__(256) void k_ffn2(const float* __restrict__ hid, const float* __restrict__ W2t,
                                              const float* __restrict__ b2, float* __restrict__ out) {
  const int b0 = blockIdx.x * 2;
  const int t = threadIdx.x, wave = t >> 6, lane = t & 63;
  float4 h0[8], h1[8];
  const float* r0 = hid + (size_t)b0 * FFN_;
#pragma unroll
  for (int j = 0; j < 8; j++) {
    h0[j] = *(const float4*)&r0[lane * 4 + j * 256];
    h1[j] = *(const float4*)&r0[FFN_ + lane * 4 + j * 256];
  }
  for (int n = wave; n < OUT_; n += 4) {
    const float* wrow = W2t + (size_t)n * FFN_;
    float s0 = 0.f, s1 = 0.f;
#pragma unroll
    for (int j = 0; j < 8; j++) {
      float4 w4 = *(const float4*)&wrow[lane * 4 + j * 256];
      s0 += w4.x * h0[j].x + w4.y * h0[j].y + w4.z * h0[j].z + w4.w * h0[j].w;
      s1 += w4.x * h1[j].x + w4.y * h1[j].y + w4.z * h1[j].z + w4.w * h1[j].w;
    }
    s0 = wred_sum(s0);
    s1 = wred_sum(s1);
    if (lane == 0) {
      out[(size_t)b0 * OUT_ + n] = s0 + b2[n];
      out[(size_t)(b0 + 1) * OUT_ + n] = s1 + b2[n];
    }
  }
}

extern "C" void kernel_launch(void* const* d_in, const int* in_sizes, int n_in,
                              void* d_out, int out_size, void* d_ws, size_t ws_size,
                              hipStream_t stream) {
  const float* lo = (const float*)d_in[0];
  const float* ro = (const float*)d_in[1];
  const float* la = (const float*)d_in[2];
  const float* ra = (const float*)d_in[3];
  const float* noise = (const float*)d_in[6];
  const float* w_i_w = (const float*)d_in[7];
  const float* w_i_b = (const float*)d_in[8];
  const float* prj_w = (const float*)d_in[9];
  const float* prj_b = (const float*)d_in[10];
  const float* W1 = (const float*)d_in[11];
  const float* b1 = (const float*)d_in[12];
  const float* W2 = (const float*)d_in[13];
  const float* b2 = (const float*)d_in[14];

  float* out = (float*)d_out;
  float* o_logits = out;                  // [1024,86]
  float* o_hout  = out + 88064;           // [1024,512]
  float* o_hpert = o_hout + 524288;       // [1024,512]
  float* o_ls    = o_hpert + 524288;      // [65536]
  float* o_rs    = o_ls + 65536;          // [65536]
  float* o_lo    = o_rs + 65536;          // [1024,512]
  float* o_ro    = o_lo + 524288;         // [1024,512]

  float* ws = (float*)d_ws;
  float* T    = ws; ws += 2048 * 512;     // [ro;lo] @ prj_w + prj_b
  float* uLR  = ws; ws += 2048 * 512;     // T @ w_i_w^T
  float* sraw = ws; ws += 2048 * 64;      // raw scores
  float* pL   = ws; ws += B_ * H_;
  float* pR   = ws; ws += B_ * H_;
  float* hid  = ws; ws += B_ * FFN_;
  float* W2t  = ws; ws += OUT_ * FFN_;
  bf16_t* pairbf = (bf16_t*)ws; ws += B_ * 1024 / 2;
  bf16_t* W1t    = (bf16_t*)ws; ws += FFN_ * 1024 / 2;
  float* ev   = ws; ws += 512;
  float* cL   = ws; ws += 1024;
  float* cR   = ws; ws += 1024;
  float* c0   = ws; ws += 4;

  k_prep<<<513, 64, 0, stream>>>(w_i_b, prj_w, prj_b, ev, c0);
  // T = [ro;lo] @ prj_w + prj_b   (NN, 2048x512x512)
  gemm64<false, true><<<dim3(32, 8), 256, 0, stream>>>(ro, lo, 1024, prj_w, prj_b, T, 512, 512);
  // uLR = T @ w_i_w^T             (NT, 2048x512x512)
  gemm64<true, false><<<dim3(32, 8), 256, 0, stream>>>(T, T, 1 << 30, w_i_w, nullptr, uLR, 512, 512);
  k_cvec<<<dim3(1024, 2), 64, 0, stream>>>(ro, lo, ev, c0, cL, cR);
  k_w1t<<<dim3(64, 32), 256, 0, stream>>>(W1, W1t);
  k_sraw<<<2048, 256, 0, stream>>>(la, ra, uLR, cL, cR, sraw);
  k_smax<<<2048, 64, 0, stream>>>(sraw, o_ls, o_rs);
  k_pool<<<2048, 256, 0, stream>>>(la, ra, o_ls, o_rs, pL, pR);
  k_pert<<<1024, 512, 0, stream>>>(lo, ro, noise, pL, pR, o_hout, o_hpert, pairbf);
  k_ffn1<<<dim3(16, 32), 256, 0, stream>>>(pairbf, W1t, b1, hid);
  k_w2t<<<688, 256, 0, stream>>>(W2, W2t);
  k_ffn2<<<512, 256, 0, stream>>>(hid, W2t, b2, o_logits);
  hipMemcpyAsync(o_lo, lo, (size_t)B_ * H_ * 4, hipMemcpyDeviceToDevice, stream);
  hipMemcpyAsync(o_ro, ro, (size_t)B_ * H_ * 4, hipMemcpyDeviceToDevice, stream);
}

// Round 10
// 164.798 us; speedup vs baseline: 1.8748x; 1.3279x over previous
//
#include <hip/hip_runtime.h>
#include <hip/hip_bf16.h>
#include <float.h>

#define B_ 1024
#define H_ 512
#define N_ (B_ * 64)
#define FFN_ 2048
#define OUT_ 86

typedef __bf16 bf16_t;
typedef __attribute__((ext_vector_type(8))) __bf16 bf16x8;
typedef __attribute__((ext_vector_type(4))) float f32x4;

__device__ __forceinline__ float wred_sum(float v) {
#pragma unroll
  for (int m = 32; m; m >>= 1) v += __shfl_xor(v, m);
  return v;
}

__device__ __forceinline__ void gload_lds16(const void* g, void* l) {
  __builtin_amdgcn_global_load_lds((const __attribute__((address_space(1))) unsigned int*)g,
                                   (__attribute__((address_space(3))) unsigned int*)l, 16, 0, 0);
}

// f32 tiled GEMM, 64x64 tile, BK=16, 4x4 accum. A split across two row blocks.
template <bool BT, bool BIAS>
__global__ __launch_bounds__(256) void gemm64(const float* __restrict__ A1, const float* __restrict__ A2,
                                              int M1, const float* __restrict__ Bm,
                                              const float* __restrict__ bias, float* __restrict__ C,
                                              int N, int K) {
  __shared__ float As[16][68];
  __shared__ float Bs[16][68];
  const int bm = blockIdx.x * 64, bn = blockIdx.y * 64;
  const float* __restrict__ A = (bm < M1) ? (A1 + (size_t)bm * K) : (A2 + (size_t)(bm - M1) * K);
  const int t = threadIdx.x;
  const int tx = t & 15, ty = t >> 4;
  float acc[4][4] = {};
  for (int k0 = 0; k0 < K; k0 += 16) {
#pragma unroll
    for (int i = 0; i < 4; i++) {
      int m = (t >> 4) + i * 16;
      As[t & 15][m] = A[(size_t)m * K + k0 + (t & 15)];
    }
    if (BT) {
#pragma unroll
      for (int i = 0; i < 4; i++) {
        int n = (t >> 4) + i * 16;
        Bs[t & 15][n] = Bm[(size_t)(bn + n) * K + k0 + (t & 15)];
      }
    } else {
#pragma unroll
      for (int i = 0; i < 4; i++) {
        int kk = (t >> 6) + i * 4;
        Bs[kk][t & 63] = Bm[(size_t)(k0 + kk) * N + bn + (t & 63)];
      }
    }
    __syncthreads();
#pragma unroll
    for (int kk = 0; kk < 16; kk++) {
      float4 av = *(const float4*)&As[kk][ty * 4];
      float4 bv = *(const float4*)&Bs[kk][tx * 4];
      float a_[4] = {av.x, av.y, av.z, av.w};
      float b_[4] = {bv.x, bv.y, bv.z, bv.w};
#pragma unroll
      for (int i = 0; i < 4; i++)
#pragma unroll
        for (int j = 0; j < 4; j++) acc[i][j] += a_[i] * b_[j];
    }
    __syncthreads();
  }
#pragma unroll
  for (int i = 0; i < 4; i++) {
    int m = bm + ty * 4 + i;
    float tmp[4];
#pragma unroll
    for (int j = 0; j < 4; j++) {
      float x = acc[i][j];
      if (BIAS) x += bias[bn + tx * 4 + j];
      tmp[j] = x;
    }
    float4 v;
    v.x = tmp[0]; v.y = tmp[1]; v.z = tmp[2]; v.w = tmp[3];
    *(float4*)&C[(size_t)m * N + bn + tx * 4] = v;
  }
}

// Fused scores+softmax+pool, single pass over atoms via counted-vmcnt LDS pipeline.
// Block per (b,side); wave w owns atoms [16w,16w+16) as 8 chunks of 2 atoms,
// double-buffered 4KB LDS per wave, global_load_lds staging (zero VGPR cost),
// s_waitcnt vmcnt(4) keeps 4 loads in flight across every compute phase.
// Online softmax per wave (softmax shift-invariance: the +cb constant cancels,
// so the old k_prep/k_cvec are deleted). Flash 4-way merge at end; the 32KB
// stream buffer is reused as the merge scratch after the barrier.
__global__ __launch_bounds__(256) void k_atoms6(const float* __restrict__ atomL, const float* __restrict__ atomR,
                                                const float* __restrict__ uLR,
                                                float* __restrict__ scoresL, float* __restrict__ scoresR,
                                                float* __restrict__ pL, float* __restrict__ pR) {
  const int pair = blockIdx.x;                 // 0..2047
  const int side = pair >> 10, b = pair & 1023;
  const int t = threadIdx.x, wave = t >> 6, lane = t & 63;

  __shared__ __align__(16) float sbuf[4][2][2][512];  // 32KB [wave][dbuf][atom][col]
  __shared__ float s_raw[64];
  __shared__ float mz[4][2];

  const float* __restrict__ atom = side ? atomR : atomL;
  const float* __restrict__ u = uLR + (size_t)pair * H_;
  float ur[8];
  *(f32x4*)&ur[0] = *(const f32x4*)&u[lane * 8];
  *(f32x4*)&ur[4] = *(const f32x4*)&u[lane * 8 + 4];

  const char* gbase = (const char*)(atom + ((size_t)b * 64 + wave * 16) * H_);

  // prologue: stage chunk 0 (atoms 0,1 of this wave) into dbuf 0
  {
    char* lb = (char*)&sbuf[wave][0][0][0];
    gload_lds16(gbase + lane * 16, lb + lane * 16);
    gload_lds16(gbase + 1024 + lane * 16, lb + 1024 + lane * 16);
    gload_lds16(gbase + 2048 + lane * 16, lb + 2048 + lane * 16);
    gload_lds16(gbase + 3072 + lane * 16, lb + 3072 + lane * 16);
  }

  float q[8] = {};
  float m_run = -FLT_MAX, z_run = 0.f, myraw = 0.f;

#pragma unroll
  for (int c = 0; c < 8; c++) {
    if (c < 7) {  // issue next chunk BEFORE consuming current; 4 stay in flight
      const char* gb = gbase + (size_t)(c + 1) * 4096;
      char* lb = (char*)&sbuf[wave][(c + 1) & 1][0][0];
      gload_lds16(gb + lane * 16, lb + lane * 16);
      gload_lds16(gb + 1024 + lane * 16, lb + 1024 + lane * 16);
      gload_lds16(gb + 2048 + lane * 16, lb + 2048 + lane * 16);
      gload_lds16(gb + 3072 + lane * 16, lb + 3072 + lane * 16);
      asm volatile("s_waitcnt vmcnt(4)" ::: "memory");
    } else {
      asm volatile("s_waitcnt vmcnt(0)" ::: "memory");
    }
    __builtin_amdgcn_sched_barrier(0);
    const float* bc = &sbuf[wave][c & 1][0][0];
    float a0[8], a1[8];
    *(f32x4*)&a0[0] = *(const f32x4*)(bc + lane * 8);
    *(f32x4*)&a0[4] = *(const f32x4*)(bc + lane * 8 + 4);
    *(f32x4*)&a1[0] = *(const f32x4*)(bc + 512 + lane * 8);
    *(f32x4*)&a1[4] = *(const f32x4*)(bc + 512 + lane * 8 + 4);
    float d0 = 0.f, d1 = 0.f;
#pragma unroll
    for (int j = 0; j < 8; j++) { d0 += a0[j] * ur[j]; d1 += a1[j] * ur[j]; }
    d0 = wred_sum(d0);
    d1 = wred_sum(d1);
    myraw = (lane == wave * 16 + c * 2) ? d0 : myraw;
    myraw = (lane == wave * 16 + c * 2 + 1) ? d1 : myraw;
    float m_new = fmaxf(m_run, fmaxf(d0, d1));
    float r = __expf(m_run - m_new);
    float e0 = __expf(d0 - m_new), e1 = __expf(d1 - m_new);
    z_run = z_run * r + e0 + e1;
    m_run = m_new;
#pragma unroll
    for (int j = 0; j < 8; j++) q[j] = q[j] * r + e0 * a0[j] + e1 * a1[j];
  }

  if (lane == 0) { mz[wave][0] = m_run; mz[wave][1] = z_run; }
  if ((lane >> 4) == wave) s_raw[lane] = myraw;  // lanes [16w,16w+16) hold this wave's raws
  __syncthreads();

  const float M = fmaxf(fmaxf(mz[0][0], mz[1][0]), fmaxf(mz[2][0], mz[3][0]));
  const float Z = mz[0][1] * __expf(mz[0][0] - M) + mz[1][1] * __expf(mz[1][0] - M) +
                  mz[2][1] * __expf(mz[2][0] - M) + mz[3][1] * __expf(mz[3][0] - M);
  const float zinv = 1.f / Z;
  const float f = __expf(m_run - M);  // wave-uniform

  float* pp = &sbuf[0][0][0][0];  // reuse stream buffers as merge scratch (post-barrier)
  f32x4 q0 = {q[0] * f, q[1] * f, q[2] * f, q[3] * f};
  f32x4 q1 = {q[4] * f, q[5] * f, q[6] * f, q[7] * f};
  *(f32x4*)&pp[wave * 512 + lane * 8] = q0;
  *(f32x4*)&pp[wave * 512 + lane * 8 + 4] = q1;
  __syncthreads();

  float v0 = (pp[t] + pp[512 + t] + pp[1024 + t] + pp[1536 + t]) * zinv;
  float v1 = (pp[t + 256] + pp[512 + t + 256] + pp[1024 + t + 256] + pp[1536 + t + 256]) * zinv;
  float* p = (side ? pR : pL) + (size_t)b * H_;
  p[t] = v0;
  p[t + 256] = v1;
  if (t < 64) (side ? scoresR : scoresL)[(size_t)b * 64 + t] = __expf(s_raw[t] - M) * zinv;
}

// perturbation + bf16 pair assembly
__global__ __launch_bounds__(512) void k_pert(const float* __restrict__ lo, const float* __restrict__ ro,
                                              const float* __restrict__ noise,
                                              const float* __restrict__ pL, const float* __restrict__ pR,
                                              float* __restrict__ h_out, float* __restrict__ h_pert,
                                              bf16_t* __restrict__ pairbf) {
  const int b = blockIdx.x, t = threadIdx.x;
  float nv = noise[(size_t)b * H_ + t];
  float sq = nv * nv;
  sq = wred_sum(sq);
  __shared__ float red[8];
  if ((t & 63) == 0) red[t >> 6] = sq;
  __syncthreads();
  float tot = 0.f;
#pragma unroll
  for (int i = 0; i < 8; i++) tot += red[i];
  float nrm = fmaxf(sqrtf(tot), 1e-12f);
  float nn = nv / nrm * 0.1f;
  float h = ro[(size_t)b * H_ + t] * pL[(size_t)b * H_ + t];
  float tt = lo[(size_t)b * H_ + t] * pR[(size_t)b * H_ + t];
  float sh = (h > 0.f) ? 1.f : ((h < 0.f) ? -1.f : 0.f);
  float st = (tt > 0.f) ? 1.f : ((tt < 0.f) ? -1.f : 0.f);
  float hp = h + sh * nn;
  float tp = tt + st * nn;
  h_out[(size_t)b * H_ + t] = h;
  h_pert[(size_t)b * H_ + t] = hp;
  pairbf[(size_t)b * 1024 + t] = (bf16_t)hp;
  pairbf[(size_t)b * 1024 + 512 + t] = (bf16_t)tp;
}

// W1 [1024][2048] f32 -> W1t [2048][1024] bf16 (transpose + cast, LDS tiled)
__global__ __launch_bounds__(256) void k_w1t(const float* __restrict__ W1, bf16_t* __restrict__ W1t) {
  __shared__ float tile[32][33];
  const int bx = blockIdx.x;
  const int by = blockIdx.y;
  const int tx = threadIdx.x & 31, ty = threadIdx.x >> 5;
#pragma unroll
  for (int i = ty; i < 32; i += 8)
    tile[i][tx] = W1[(size_t)(by * 32 + i) * FFN_ + bx * 32 + tx];
  __syncthreads();
#pragma unroll
  for (int i = ty; i < 32; i += 8)
    W1t[(size_t)(bx * 32 + i) * 1024 + by * 32 + tx] = (bf16_t)tile[tx][i];
}

// FFN1 via MFMA bf16 (64x64 tile, XOR-swizzled source + matching swizzled read)
__global__ __launch_bounds__(256) void k_ffn1(const bf16_t* __restrict__ Abf, const bf16_t* __restrict__ Bt,
                                              const float* __restrict__ bias, float* __restrict__ C) {
  __shared__ bf16_t As[64 * 64];
  __shared__ bf16_t Bs[64 * 64];
  const int bm = blockIdx.x * 64, bn = blockIdx.y * 64;
  const int t = threadIdx.x;
  const int lane = t & 63, wave = t >> 6;
  const int wm = wave & 1, wn = wave >> 1;
  const int l15 = lane & 15, l4 = lane >> 4;
  f32x4 acc[2][2] = {{{0.f, 0.f, 0.f, 0.f}, {0.f, 0.f, 0.f, 0.f}},
                     {{0.f, 0.f, 0.f, 0.f}, {0.f, 0.f, 0.f, 0.f}}};

  for (int k0 = 0; k0 < 1024; k0 += 64) {
#pragma unroll
    for (int r = 0; r < 2; r++) {
      const int off = (r * 256 + t) * 16;
      const int row = off >> 7;
      const int g = (off >> 4) & 7;
      const int scb = ((g ^ (row & 7)) << 4);
      gload_lds16((const char*)Abf + (size_t)(bm + row) * 2048 + k0 * 2 + scb, (char*)As + off);
      gload_lds16((const char*)Bt + (size_t)(bn + row) * 2048 + k0 * 2 + scb, (char*)Bs + off);
    }
    __syncthreads();
#pragma unroll
    for (int ks = 0; ks < 2; ks++) {
      const int ar0 = wm * 32 + l15, ar1 = ar0 + 16;
      const int br0 = wn * 32 + l15, br1 = br0 + 16;
      const int gA = ks * 4 + l4;
      bf16x8 a0 = *(const bf16x8*)((const char*)As + ar0 * 128 + ((gA ^ (ar0 & 7)) << 4));
      bf16x8 a1 = *(const bf16x8*)((const char*)As + ar1 * 128 + ((gA ^ (ar1 & 7)) << 4));
      bf16x8 b0 = *(const bf16x8*)((const char*)Bs + br0 * 128 + ((gA ^ (br0 & 7)) << 4));
      bf16x8 b1 = *(const bf16x8*)((const char*)Bs + br1 * 128 + ((gA ^ (br1 & 7)) << 4));
      acc[0][0] = __builtin_amdgcn_mfma_f32_16x16x32_bf16(a0, b0, acc[0][0], 0, 0, 0);
      acc[0][1] = __builtin_amdgcn_mfma_f32_16x16x32_bf16(a0, b1, acc[0][1], 0, 0, 0);
      acc[1][0] = __builtin_amdgcn_mfma_f32_16x16x32_bf16(a1, b0, acc[1][0], 0, 0, 0);
      acc[1][1] = __builtin_amdgcn_mfma_f32_16x16x32_bf16(a1, b1, acc[1][1], 0, 0, 0);
    }
    __syncthreads();
  }
#pragma unroll
  for (int mi = 0; mi < 2; mi++)
#pragma unroll
    for (int nj = 0; nj < 2; nj++)
#pragma unroll
      for (int r = 0; r < 4; r++) {
        const int m = bm + wm * 32 + mi * 16 + l4 * 4 + r;
        const int n = bn + wn * 32 + nj * 16 + l15;
        float v = acc[mi][nj][r] + bias[n];
        C[(size_t)m * FFN_ + n] = fmaxf(v, 0.f);
      }
}

__global__ void k_w2t(const float* __restrict__ W2, float* __restrict__ W2t) {
  int idx = blockIdx.x * 256 + threadIdx.x;
  if (idx < OUT_ * FFN_) {
    int n = idx / FFN_, k = idx % FFN_;
    W2t[idx] = W2[(size_t)k * OUT_ + n];
  }
}

__global__ __launch_bounds__(256) void k_ffn2(const float* __restrict__ hid, const float* __restrict__ W2t,
                                              const float* __restrict__ b2, float* __restrict__ out) {
  const int b0 = blockIdx.x * 2;
  const int t = threadIdx.x, wave = t >> 6, lane = t & 63;
  float4 h0[8], h1[8];
  const float* r0 = hid + (size_t)b0 * FFN_;
#pragma unroll
  for (int j = 0; j < 8; j++) {
    h0[j] = *(const float4*)&r0[lane * 4 + j * 256];
    h1[j] = *(const float4*)&r0[FFN_ + lane * 4 + j * 256];
  }
  for (int n = wave; n < OUT_; n += 4) {
    const float* wrow = W2t + (size_t)n * FFN_;
    float s0 = 0.f, s1 = 0.f;
#pragma unroll
    for (int j = 0; j < 8; j++) {
      float4 w4 = *(const float4*)&wrow[lane * 4 + j * 256];
      s0 += w4.x * h0[j].x + w4.y * h0[j].y + w4.z * h0[j].z + w4.w * h0[j].w;
      s1 += w4.x * h1[j].x + w4.y * h1[j].y + w4.z * h1[j].z + w4.w * h1[j].w;
    }
    s0 = wred_sum(s0);
    s1 = wred_sum(s1);
    if (lane == 0) {
      out[(size_t)b0 * OUT_ + n] = s0 + b2[n];
      out[(size_t)(b0 + 1) * OUT_ + n] = s1 + b2[n];
    }
  }
}

extern "C" void kernel_launch(void* const* d_in, const int* in_sizes, int n_in,
                              void* d_out, int out_size, void* d_ws, size_t ws_size,
                              hipStream_t stream) {
  const float* lo = (const float*)d_in[0];
  const float* ro = (const float*)d_in[1];
  const float* la = (const float*)d_in[2];
  const float* ra = (const float*)d_in[3];
  const float* noise = (const float*)d_in[6];
  const float* w_i_w = (const float*)d_in[7];
  const float* prj_w = (const float*)d_in[9];
  const float* prj_b = (const float*)d_in[10];
  const float* W1 = (const float*)d_in[11];
  const float* b1 = (const float*)d_in[12];
  const float* W2 = (const float*)d_in[13];
  const float* b2 = (const float*)d_in[14];

  float* out = (float*)d_out;
  float* o_logits = out;                  // [1024,86]
  float* o_hout  = out + 88064;           // [1024,512]
  float* o_hpert = o_hout + 524288;       // [1024,512]
  float* o_ls    = o_hpert + 524288;      // [65536]
  float* o_rs    = o_ls + 65536;          // [65536]
  float* o_lo    = o_rs + 65536;          // [1024,512]
  float* o_ro    = o_lo + 524288;         // [1024,512]

  float* ws = (float*)d_ws;
  float* T    = ws; ws += 2048 * 512;     // [ro;lo] @ prj_w + prj_b
  float* uLR  = ws; ws += 2048 * 512;     // T @ w_i_w^T
  float* pL   = ws; ws += B_ * H_;
  float* pR   = ws; ws += B_ * H_;
  float* hid  = ws; ws += B_ * FFN_;
  float* W2t  = ws; ws += OUT_ * FFN_;
  bf16_t* pairbf = (bf16_t*)ws; ws += B_ * 1024 / 2;
  bf16_t* W1t    = (bf16_t*)ws; ws += FFN_ * 1024 / 2;

  // T = [ro;lo] @ prj_w + prj_b   (NN, 2048x512x512)
  gemm64<false, true><<<dim3(32, 8), 256, 0, stream>>>(ro, lo, 1024, prj_w, prj_b, T, 512, 512);
  // uLR = T @ w_i_w^T             (NT, 2048x512x512; bias dv cancels in softmax)
  gemm64<true, false><<<dim3(32, 8), 256, 0, stream>>>(T, T, 1 << 30, w_i_w, nullptr, uLR, 512, 512);
  k_w1t<<<dim3(64, 32), 256, 0, stream>>>(W1, W1t);
  k_atoms6<<<2048, 256, 0, stream>>>(la, ra, uLR, o_ls, o_rs, pL, pR);
  k_pert<<<1024, 512, 0, stream>>>(lo, ro, noise, pL, pR, o_hout, o_hpert, pairbf);
  k_ffn1<<<dim3(16, 32), 256, 0, stream>>>(pairbf, W1t, b1, hid);
  k_w2t<<<688, 256, 0, stream>>>(W2, W2t);
  k_ffn2<<<512, 256, 0, stream>>>(hid, W2t, b2, o_logits);
  hipMemcpyAsync(o_lo, lo, (size_t)B_ * H_ * 4, hipMemcpyDeviceToDevice, stream);
  hipMemcpyAsync(o_ro, ro, (size_t)B_ * H_ * 4, hipMemcpyDeviceToDevice, stream);
}